// Round 6
// baseline (1672.791 us; speedup 1.0000x reference)
//
#include <hip/hip_runtime.h>
#include <stdint.h>
#include <stddef.h>

typedef _Float16 f16;
typedef f16 f16x8 __attribute__((ext_vector_type(8)));
typedef float f32x4 __attribute__((ext_vector_type(4)));

#define STRIDE 616          // LDS row stride (f16): 1232 B; 308 dwords, 308%32=20 -> spreads banks
#define BATCH 131072

// Per-layer dims: (o, k); kpad = align32(k); opad = align128(o) = T*8*16
static constexpr int  LO[10]  = {600,600,160,600,600,379,40,40,40,2};
static constexpr int  LK[10]  = {379,600,600,80,600,600,160,40,40,40};
static constexpr int  LKP[10] = {384,608,608,96,608,608,160,64,64,64};
static constexpr long WOFF[11] = {0,245760,634880,790528,851968,1241088,1474560,1495040,1503232,1511424,1519616};
#define WTOTAL 1519616      // f16 elems (~2.9 MB in d_ws)

// ---------------------------------------------------------------------------
// int32 [o][k] -> f16 padded [opad][kpad], exact integer values.
// ---------------------------------------------------------------------------
struct ConvArgs { const int* w[10]; f16* dst; };

__global__ __launch_bounds__(256) void convert_weights(ConvArgs a) {
  long e8 = ((long)blockIdx.x * 256 + threadIdx.x) * 8;
#pragma unroll
  for (int l = 0; l < 10; ++l) {
    if (e8 >= WOFF[l] && e8 < WOFF[l + 1]) {
      int local = (int)(e8 - WOFF[l]);
      int o  = local / LKP[l];
      int k0 = local - o * LKP[l];
      const int* w = a.w[l];
      f16 v8[8];
#pragma unroll
      for (int j = 0; j < 8; ++j) {
        int k = k0 + j;
        int iv = (o < LO[l] && k < LK[l]) ? w[o * LK[l] + k] : 0;
        v8[j] = (f16)(float)iv;
      }
      *(f16x8*)(a.dst + e8) = *(const f16x8*)v8;
    }
  }
}

// ---------------------------------------------------------------------------
__device__ __forceinline__ float act_elu(float x)  { return x > 0.f ? x : __expf(x) - 1.f; }
__device__ __forceinline__ float act_tanh(float x) {
  float s = __expf(-2.f * fabsf(x));
  float t = (1.f - s) * __builtin_amdgcn_rcpf(1.f + s);
  return x >= 0.f ? t : -t;
}
__device__ __forceinline__ float act_softplus(float x) {
  return fmaxf(x, 0.f) + __logf(1.f + __expf(-fabsf(x)));
}
__device__ __forceinline__ float act_sigmoid(float x) {
  return __builtin_amdgcn_rcpf(1.f + __expf(-x));
}

// ---------------------------------------------------------------------------
// One fused linear layer on the 64-row LDS tile, 16 waves.
//
// Evidence trail (R1-R8):
//  - 512-thr blocks never co-schedule 2 blocks/CU here (R1/R6/R7, ~24% occ).
//  - 1024-thr block reaches 48% occ (R5/R8) but BOTH __launch_bounds__(1024,4)
//    and plain (1024) yield VGPR=64: the backend derives waves-per-EU range
//    (min=4, max=8) from the 16-wave block and the allocator targets MAX=8
//    (64 VGPR), paying ~380MB/dispatch scratch spill (FETCH/WRITE signature
//    identical in R5 and R8: 1.046e9 B) and serializing the k-pipeline.
//  - R9: pin amdgpu_waves_per_eu(4,4) -> cap 512/4 = 128 VGPR. LDS (157.7KB)
//    already limits to 1 block/CU, so occupancy >4 waves/EU is unreachable
//    anyway; trading registers for it was pure loss.
//
// Wave (wn = w&7, wm = w>>3): wn picks N-tiles {wn, wn+8,...} (16 cols),
// wm picks 2-of-4 M-tiles (rows wm*32..+31). Depth-1 k-pipeline: loads for
// k-step kk+1 issue before MFMAs of kk (named double buffers, parity branch,
// all indices compile-time).
//
// MFMA 16x16x32 f16: A[m=lane&15][k=(lane>>4)*8+j], B[k][n]=W[n][k] (8
// contiguous k per lane), C/D col=lane&15 row=(lane>>4)*4+i (verified R3).
// ACT: 1=elu->LDS, 2=tanh->LDS, 5=L2 (mu raw / softplus sigma -> LDS+global),
//      6=sigmoid(softplus)->global, 7=softplus->global
// ---------------------------------------------------------------------------
template <int ACT, int T, int KP>
__device__ __forceinline__ void gemm_layer(
    const f16* __restrict__ Wf, const float* __restrict__ sv, const float* __restrict__ bv,
    int o_real,
    const f16* lin, f16* lout, int out_cols,
    float* __restrict__ g0, float* __restrict__ g1, long row0, int gw,
    int wn, int wm, int lrow, int lq) {
  f32x4 acc[T][2];
#pragma unroll
  for (int t = 0; t < T; ++t)
#pragma unroll
    for (int m = 0; m < 2; ++m) acc[t][m] = (f32x4){0.f, 0.f, 0.f, 0.f};

  const f16* ap = lin + (wm * 32 + lrow) * STRIDE + lq * 8;
  const f16* bp[T];
#pragma unroll
  for (int t = 0; t < T; ++t) {
    int n = (wn + 8 * t) * 16 + lrow;
    bp[t] = Wf + (size_t)n * KP + lq * 8;
  }

  constexpr int NK = KP / 32;  // all layers have NK >= 2
  f16x8 a0[2], a1[2], b0[T], b1[T];

  // prologue: k-step 0 into buffer 0
#pragma unroll
  for (int m = 0; m < 2; ++m) a0[m] = *(const f16x8*)(ap + m * 16 * STRIDE);
#pragma unroll
  for (int t = 0; t < T; ++t) b0[t] = *(const f16x8*)(bp[t]);

#pragma unroll
  for (int kk = 0; kk < NK; ++kk) {
    const int kn = (kk + 1) * 32;
    if ((kk & 1) == 0) {
      if (kk + 1 < NK) {
#pragma unroll
        for (int m = 0; m < 2; ++m) a1[m] = *(const f16x8*)(ap + m * 16 * STRIDE + kn);
#pragma unroll
        for (int t = 0; t < T; ++t) b1[t] = *(const f16x8*)(bp[t] + kn);
      }
#pragma unroll
      for (int t = 0; t < T; ++t)
#pragma unroll
        for (int m = 0; m < 2; ++m)
          acc[t][m] = __builtin_amdgcn_mfma_f32_16x16x32_f16(a0[m], b0[t], acc[t][m], 0, 0, 0);
    } else {
      if (kk + 1 < NK) {
#pragma unroll
        for (int m = 0; m < 2; ++m) a0[m] = *(const f16x8*)(ap + m * 16 * STRIDE + kn);
#pragma unroll
        for (int t = 0; t < T; ++t) b0[t] = *(const f16x8*)(bp[t] + kn);
      }
#pragma unroll
      for (int t = 0; t < T; ++t)
#pragma unroll
        for (int m = 0; m < 2; ++m)
          acc[t][m] = __builtin_amdgcn_mfma_f32_16x16x32_f16(a1[m], b1[t], acc[t][m], 0, 0, 0);
    }
  }

#pragma unroll
  for (int t = 0; t < T; ++t) {
    int n = (wn + 8 * t) * 16 + lrow;
    bool nv = n < o_real;
    float sc = nv ? sv[n] * (1.f / 127.f) : 0.f;
    float bb = nv ? bv[n] : 0.f;
#pragma unroll
    for (int m = 0; m < 2; ++m) {
#pragma unroll
      for (int i = 0; i < 4; ++i) {
        int row = wm * 32 + m * 16 + lq * 4 + i;
        float v = acc[t][m][i] * sc + bb;
        if (ACT == 1 || ACT == 2) {
          float r = (ACT == 1) ? act_elu(v) : act_tanh(v);
          if (n < out_cols) lout[row * STRIDE + n] = nv ? (f16)r : (f16)0.f;
        } else if (ACT == 5) {
          if (n < 80) {
            g0[(row0 + row) * 80 + n] = v;
            lout[row * STRIDE + n] = (f16)v;
          } else if (n < 160) {
            float sp = act_softplus(v);
            g1[(row0 + row) * 80 + (n - 80)] = sp;
            lout[row * STRIDE + n] = (f16)sp;
          }
        } else if (ACT == 6) {
          if (nv) g0[(row0 + row) * gw + n] = act_sigmoid(act_softplus(v));
        } else if (ACT == 7) {
          if (nv) g0[(row0 + row) * gw + n] = act_softplus(v);
        }
      }
    }
  }
  __syncthreads();
}

// ---------------------------------------------------------------------------
struct FusedArgs {
  const float* x; const float* eps;
  const f16* wf[10];
  const float* s[10]; const float* b[10];
  float* mlp; float* vae; float* mu; float* sig;
};

__global__ __launch_bounds__(1024)
__attribute__((amdgpu_waves_per_eu(4, 4)))
void fused_kernel(FusedArgs A) {
  extern __shared__ char smem[];
  f16* bufA = (f16*)smem;
  f16* bufB = bufA + 64 * STRIDE;
  const int tid  = threadIdx.x;
  const int lane = tid & 63;
  const int w    = tid >> 6;       // 0..15
  const int wn   = w & 7;          // N-group
  const int wm   = w >> 3;         // M-group (0: rows 0-31, 1: rows 32-63)
  const int lrow = lane & 15, lq = lane >> 4;
  const long row0 = (long)blockIdx.x * 64;

#define GLAYER(ACTV, T, L, IN, OUT, OUTC, G0, G1, GW) \
  gemm_layer<ACTV, T, LKP[L]>(A.wf[L], A.s[L], A.b[L], LO[L], \
      IN, OUT, OUTC, G0, G1, row0, GW, wn, wm, lrow, lq)

  // stage x (fp32 [B,379]) -> bufA f16, cols 379..383 zeroed
  for (int idx = tid; idx < 64 * 384; idx += 1024) {
    int r = idx / 384, c = idx - r * 384;
    float v = (c < 379) ? A.x[(row0 + r) * 379 + c] : 0.f;
    bufA[r * STRIDE + c] = (f16)v;
  }
  __syncthreads();

  // encoder
  GLAYER(1, 5, 0, bufA, bufB, 608, nullptr, nullptr, 0);
  GLAYER(2, 5, 1, bufB, bufA, 608, nullptr, nullptr, 0);
  GLAYER(5, 2, 2, bufA, bufB, 160, A.mu, A.sig, 0);

  // z = fp16(mu + sigma*eps) -> bufA cols [0,96)
  for (int idx = tid; idx < 64 * 96; idx += 1024) {
    int r = idx / 96, c = idx - r * 96;
    float zv = 0.f;
    if (c < 80) {
      float muv = (float)bufB[r * STRIDE + c];
      float sgv = (float)bufB[r * STRIDE + 80 + c];
      zv = muv + sgv * A.eps[(row0 + r) * 80 + c];
    }
    bufA[r * STRIDE + c] = (f16)zv;
  }
  __syncthreads();

  // m-chain (input bufB cols [0,160) = [mu | softplus(sigma)])
  GLAYER(2, 1, 6, bufB, bufA + 128, 64, nullptr, nullptr, 0);
  GLAYER(1, 1, 7, bufA + 128, bufB, 64, nullptr, nullptr, 0);
  GLAYER(1, 1, 8, bufB, bufA + 192, 64, nullptr, nullptr, 0);
  GLAYER(7, 1, 9, bufA + 192, nullptr, 0, A.mlp, nullptr, 2);

  // d-chain (input z = bufA cols [0,96))
  GLAYER(2, 5, 3, bufA, bufB, 608, nullptr, nullptr, 0);
  GLAYER(1, 5, 4, bufB, bufA, 608, nullptr, nullptr, 0);
  GLAYER(6, 3, 5, bufA, nullptr, 0, A.vae, nullptr, 379);
#undef GLAYER
}

// ---------------------------------------------------------------------------
extern "C" void kernel_launch(void* const* d_in, const int* in_sizes, int n_in,
                              void* d_out, int out_size, void* d_ws, size_t ws_size,
                              hipStream_t stream) {
  (void)in_sizes; (void)n_in; (void)out_size; (void)ws_size;

  f16* wf = (f16*)d_ws;

  ConvArgs ca;
  for (int l = 0; l < 10; ++l) ca.w[l] = (const int*)d_in[2 + 3 * l];
  ca.dst = wf;
  hipLaunchKernelGGL(convert_weights, dim3(742), dim3(256), 0, stream, ca);  // 742*256*8 == WTOTAL

  FusedArgs fa;
  fa.x   = (const float*)d_in[0];
  fa.eps = (const float*)d_in[1];
  for (int l = 0; l < 10; ++l) {
    fa.wf[l] = wf + WOFF[l];
    fa.s[l]  = (const float*)d_in[3 + 3 * l];
    fa.b[l]  = (const float*)d_in[4 + 3 * l];
  }
  float* out = (float*)d_out;
  fa.mlp = out;                                   // [B,2]
  fa.vae = out + (long)BATCH * 2;                 // [B,379]
  fa.mu  = out + (long)BATCH * (2 + 379);         // [B,80]
  fa.sig = out + (long)BATCH * (2 + 379 + 80);    // [B,80]

  const int lds_bytes = 2 * 64 * STRIDE * 2;      // 157696 B (1 block/CU, 16 waves)
  hipFuncSetAttribute(reinterpret_cast<const void*>(fused_kernel),
                      hipFuncAttributeMaxDynamicSharedMemorySize, lds_bytes);
  hipLaunchKernelGGL(fused_kernel, dim3(BATCH / 64), dim3(1024), lds_bytes, stream, fa);
}

// Round 7
// 1271.277 us; speedup vs baseline: 1.3158x; 1.3158x over previous
//
#include <hip/hip_runtime.h>
#include <stdint.h>
#include <stddef.h>

typedef _Float16 f16;
typedef f16 f16x4 __attribute__((ext_vector_type(4)));
typedef f16 f16x8 __attribute__((ext_vector_type(8)));
typedef float f32x4 __attribute__((ext_vector_type(4)));

#define STRIDE 616          // LDS row stride (f16): 1232 B; 308 dwords, 308%32=20 -> spreads banks
#define BATCH 131072

// Per-layer dims: (o, k); kpad = align32(k); opad = align128(o) = T*8*16
static constexpr int  LO[10]  = {600,600,160,600,600,379,40,40,40,2};
static constexpr int  LK[10]  = {379,600,600,80,600,600,160,40,40,40};
static constexpr int  LKP[10] = {384,608,608,96,608,608,160,64,64,64};
static constexpr long WOFF[11] = {0,245760,634880,790528,851968,1241088,1474560,1495040,1503232,1511424,1519616};
#define WTOTAL 1519616      // f16 elems (~2.9 MB in d_ws)

// ---------------------------------------------------------------------------
// int32 [o][k] -> f16 padded [opad][kpad], exact integer values.
// ---------------------------------------------------------------------------
struct ConvArgs { const int* w[10]; f16* dst; };

__global__ __launch_bounds__(256) void convert_weights(ConvArgs a) {
  long e8 = ((long)blockIdx.x * 256 + threadIdx.x) * 8;
#pragma unroll
  for (int l = 0; l < 10; ++l) {
    if (e8 >= WOFF[l] && e8 < WOFF[l + 1]) {
      int local = (int)(e8 - WOFF[l]);
      int o  = local / LKP[l];
      int k0 = local - o * LKP[l];
      const int* w = a.w[l];
      f16 v8[8];
#pragma unroll
      for (int j = 0; j < 8; ++j) {
        int k = k0 + j;
        int iv = (o < LO[l] && k < LK[l]) ? w[o * LK[l] + k] : 0;
        v8[j] = (f16)(float)iv;
      }
      *(f16x8*)(a.dst + e8) = *(const f16x8*)v8;
    }
  }
}

// ---------------------------------------------------------------------------
__device__ __forceinline__ float act_elu(float x)  { return x > 0.f ? x : __expf(x) - 1.f; }
__device__ __forceinline__ float act_tanh(float x) {
  float s = __expf(-2.f * fabsf(x));
  float t = (1.f - s) * __builtin_amdgcn_rcpf(1.f + s);
  return x >= 0.f ? t : -t;
}
__device__ __forceinline__ float act_softplus(float x) {
  return fmaxf(x, 0.f) + __logf(1.f + __expf(-fabsf(x)));
}
__device__ __forceinline__ float act_sigmoid(float x) {
  return __builtin_amdgcn_rcpf(1.f + __expf(-x));
}

// ---------------------------------------------------------------------------
// One fused linear layer on the 64-row LDS tile, 8 waves, full-M per wave.
//
// Evidence trail (R1-R9): best = 512thr/128VGPR/8 waves/CU (R1, 1145us).
// 1024-thr blocks always allocate 64 VGPR + ~350MB/dispatch scratch spill
// (R5/R8/R9; amdgpu_waves_per_eu(4,4) after __launch_bounds__ was ignored).
// All pipes <=20% at best config -> latency-bound on B (L2) loads; depth-1
// prefetch insufficient AND was likely demoted at the 128-VGPR cap (live set
// ~170 > 128). R10: (a) amdgpu_waves_per_eu(2,2) placed BEFORE __global__ to
// unlock 256 VGPR -- real occupancy is 2 waves/SIMD regardless (LDS caps at
// 1 block/CU), so max=2 gives up nothing; (b) depth-2 B prefetch (3 rotating
// B buffer sets, named, compile-time indices): B consumed at step kk was
// issued at kk-2 (~2 k-steps of MFMA+issue ~400-600cyc) -> covers contended
// L2 latency. A stays depth-1 (LDS ~120cyc). Live set ~190 <= 256.
//
// MFMA 16x16x32 f16: A[m=lane&15][k=(lane>>4)*8+j], B[k][n]=W[n][k] (8
// contiguous k per lane), C/D col=lane&15 row=(lane>>4)*4+i (verified R3).
// ACT: 1=elu->LDS, 2=tanh->LDS, 5=L2 (mu raw / softplus sigma -> LDS+global),
//      6=sigmoid(softplus)->global, 7=softplus->global
// ---------------------------------------------------------------------------
template <int ACT, int T, int KP>
__device__ __forceinline__ void gemm_layer(
    const f16* __restrict__ Wf, const float* __restrict__ sv, const float* __restrict__ bv,
    int o_real,
    const f16* lin, f16* lout, int out_cols,
    float* __restrict__ g0, float* __restrict__ g1, long row0, int gw,
    int w, int lrow, int lq) {
  f32x4 acc[T][4];
#pragma unroll
  for (int t = 0; t < T; ++t)
#pragma unroll
    for (int m = 0; m < 4; ++m) acc[t][m] = (f32x4){0.f, 0.f, 0.f, 0.f};

  const f16* ap = lin + lrow * STRIDE + lq * 8;
  const f16* bp[T];
#pragma unroll
  for (int t = 0; t < T; ++t) {
    int n = (w + 8 * t) * 16 + lrow;
    bp[t] = Wf + (size_t)n * KP + lq * 8;
  }

  constexpr int NK = KP / 32;  // all layers have NK >= 2
  f16x8 a0[4], a1[4], b0[T], b1[T], b2[T];

  // prologue: A k-step 0; B k-steps 0 and 1 (depth-2)
#pragma unroll
  for (int m = 0; m < 4; ++m) a0[m] = *(const f16x8*)(ap + m * 16 * STRIDE);
#pragma unroll
  for (int t = 0; t < T; ++t) b0[t] = *(const f16x8*)(bp[t]);
#pragma unroll
  for (int t = 0; t < T; ++t) b1[t] = *(const f16x8*)(bp[t] + 32);

  // steady state: at step kk, consume A(kk%2), B(kk%3); issue A for kk+1,
  // B for kk+2. All buffer names resolved at compile time via kk%6 switch.
#define KSTEP(AC, AN, BC, BN)                                                \
  {                                                                          \
    const int kn1 = (kk + 1) * 32, kn2 = (kk + 2) * 32;                      \
    if (kk + 2 < NK) {                                                       \
      _Pragma("unroll")                                                      \
      for (int t = 0; t < T; ++t) BN[t] = *(const f16x8*)(bp[t] + kn2);      \
    }                                                                        \
    if (kk + 1 < NK) {                                                       \
      _Pragma("unroll")                                                      \
      for (int m = 0; m < 4; ++m)                                            \
        AN[m] = *(const f16x8*)(ap + m * 16 * STRIDE + kn1);                 \
    }                                                                        \
    _Pragma("unroll")                                                        \
    for (int t = 0; t < T; ++t)                                              \
      _Pragma("unroll")                                                      \
      for (int m = 0; m < 4; ++m)                                            \
        acc[t][m] =                                                          \
            __builtin_amdgcn_mfma_f32_16x16x32_f16(AC[m], BC[t], acc[t][m], 0, 0, 0); \
  }

#pragma unroll
  for (int kk = 0; kk < NK; ++kk) {
    switch (kk % 6) {
      case 0: KSTEP(a0, a1, b0, b2); break;
      case 1: KSTEP(a1, a0, b1, b0); break;
      case 2: KSTEP(a0, a1, b2, b1); break;
      case 3: KSTEP(a1, a0, b0, b2); break;
      case 4: KSTEP(a0, a1, b1, b0); break;
      case 5: KSTEP(a1, a0, b2, b1); break;
    }
  }
#undef KSTEP

#pragma unroll
  for (int t = 0; t < T; ++t) {
    int n = (w + 8 * t) * 16 + lrow;
    bool nv = n < o_real;
    float sc = nv ? sv[n] * (1.f / 127.f) : 0.f;
    float bb = nv ? bv[n] : 0.f;
#pragma unroll
    for (int m = 0; m < 4; ++m) {
#pragma unroll
      for (int i = 0; i < 4; ++i) {
        int row = m * 16 + lq * 4 + i;
        float v = acc[t][m][i] * sc + bb;
        if (ACT == 1 || ACT == 2) {
          float r = (ACT == 1) ? act_elu(v) : act_tanh(v);
          if (n < out_cols) lout[row * STRIDE + n] = nv ? (f16)r : (f16)0.f;
        } else if (ACT == 5) {
          if (n < 80) {
            g0[(row0 + row) * 80 + n] = v;
            lout[row * STRIDE + n] = (f16)v;
          } else if (n < 160) {
            float sp = act_softplus(v);
            g1[(row0 + row) * 80 + (n - 80)] = sp;
            lout[row * STRIDE + n] = (f16)sp;
          }
        } else if (ACT == 6) {
          if (nv) g0[(row0 + row) * gw + n] = act_sigmoid(act_softplus(v));
        } else if (ACT == 7) {
          if (nv) g0[(row0 + row) * gw + n] = act_softplus(v);
        }
      }
    }
  }
  __syncthreads();
}

// ---------------------------------------------------------------------------
struct FusedArgs {
  const float* x; const float* eps;
  const f16* wf[10];
  const float* s[10]; const float* b[10];
  float* mlp; float* vae; float* mu; float* sig;
};

__attribute__((amdgpu_waves_per_eu(2, 2)))
__global__ __launch_bounds__(512) void fused_kernel(FusedArgs A) {
  extern __shared__ char smem[];
  f16* bufA = (f16*)smem;
  f16* bufB = bufA + 64 * STRIDE;
  const int tid  = threadIdx.x;
  const int lane = tid & 63;
  const int w    = tid >> 6;
  const int lrow = lane & 15, lq = lane >> 4;
  const long row0 = (long)blockIdx.x * 64;

#define GLAYER(ACTV, T, L, IN, OUT, OUTC, G0, G1, GW) \
  gemm_layer<ACTV, T, LKP[L]>(A.wf[L], A.s[L], A.b[L], LO[L], \
      IN, OUT, OUTC, G0, G1, row0, GW, w, lrow, lq)

  // stage x (fp32 [B,379]) -> bufA f16, cols 379..383 zeroed. float4 loads:
  // 96 groups of 4 cols; group 94 covers 376..379 (379 OOB-in-row -> scalar),
  // group 95 = pure pad.
  for (int idx = tid; idx < 64 * 96; idx += 512) {
    int r = idx / 96, c4 = idx - r * 96;
    const float* xr = A.x + (row0 + r) * 379;
    f16 o0 = (f16)0.f, o1 = (f16)0.f, o2 = (f16)0.f, o3 = (f16)0.f;
    if (c4 < 94) {
      float4 v = *(const float4*)(xr + c4 * 4);
      o0 = (f16)v.x; o1 = (f16)v.y; o2 = (f16)v.z; o3 = (f16)v.w;
    } else if (c4 == 94) {
      o0 = (f16)xr[376]; o1 = (f16)xr[377]; o2 = (f16)xr[378];
    }
    f16x4 o4 = {o0, o1, o2, o3};
    *(f16x4*)(bufA + r * STRIDE + c4 * 4) = o4;
  }
  __syncthreads();

  // encoder
  GLAYER(1, 5, 0, bufA, bufB, 608, nullptr, nullptr, 0);
  GLAYER(2, 5, 1, bufB, bufA, 608, nullptr, nullptr, 0);
  GLAYER(5, 2, 2, bufA, bufB, 160, A.mu, A.sig, 0);

  // z = fp16(mu + sigma*eps) -> bufA cols [0,96)
  for (int idx = tid; idx < 64 * 96; idx += 512) {
    int r = idx / 96, c = idx - r * 96;
    float zv = 0.f;
    if (c < 80) {
      float muv = (float)bufB[r * STRIDE + c];
      float sgv = (float)bufB[r * STRIDE + 80 + c];
      zv = muv + sgv * A.eps[(row0 + r) * 80 + c];
    }
    bufA[r * STRIDE + c] = (f16)zv;
  }
  __syncthreads();

  // m-chain (input bufB cols [0,160) = [mu | softplus(sigma)])
  GLAYER(2, 1, 6, bufB, bufA + 128, 64, nullptr, nullptr, 0);
  GLAYER(1, 1, 7, bufA + 128, bufB, 64, nullptr, nullptr, 0);
  GLAYER(1, 1, 8, bufB, bufA + 192, 64, nullptr, nullptr, 0);
  GLAYER(7, 1, 9, bufA + 192, nullptr, 0, A.mlp, nullptr, 2);

  // d-chain (input z = bufA cols [0,96))
  GLAYER(2, 5, 3, bufA, bufB, 608, nullptr, nullptr, 0);
  GLAYER(1, 5, 4, bufB, bufA, 608, nullptr, nullptr, 0);
  GLAYER(6, 3, 5, bufA, nullptr, 0, A.vae, nullptr, 379);
#undef GLAYER
}

// ---------------------------------------------------------------------------
extern "C" void kernel_launch(void* const* d_in, const int* in_sizes, int n_in,
                              void* d_out, int out_size, void* d_ws, size_t ws_size,
                              hipStream_t stream) {
  (void)in_sizes; (void)n_in; (void)out_size; (void)ws_size;

  f16* wf = (f16*)d_ws;

  ConvArgs ca;
  for (int l = 0; l < 10; ++l) ca.w[l] = (const int*)d_in[2 + 3 * l];
  ca.dst = wf;
  hipLaunchKernelGGL(convert_weights, dim3(742), dim3(256), 0, stream, ca);  // 742*256*8 == WTOTAL

  FusedArgs fa;
  fa.x   = (const float*)d_in[0];
  fa.eps = (const float*)d_in[1];
  for (int l = 0; l < 10; ++l) {
    fa.wf[l] = wf + WOFF[l];
    fa.s[l]  = (const float*)d_in[3 + 3 * l];
    fa.b[l]  = (const float*)d_in[4 + 3 * l];
  }
  float* out = (float*)d_out;
  fa.mlp = out;                                   // [B,2]
  fa.vae = out + (long)BATCH * 2;                 // [B,379]
  fa.mu  = out + (long)BATCH * (2 + 379);         // [B,80]
  fa.sig = out + (long)BATCH * (2 + 379 + 80);    // [B,80]

  const int lds_bytes = 2 * 64 * STRIDE * 2;      // 157696 B (1 block/CU, 8 waves)
  hipFuncSetAttribute(reinterpret_cast<const void*>(fused_kernel),
                      hipFuncAttributeMaxDynamicSharedMemorySize, lds_bytes);
  hipLaunchKernelGGL(fused_kernel, dim3(BATCH / 64), dim3(512), lds_bytes, stream, fa);
}